// Round 5
// baseline (70.079 us; speedup 1.0000x reference)
//
#include <hip/hip_runtime.h>

// Problem: B=4, L=256, D=768, OUT=256
//   pj[b,j,o] = sum_d text[b,j,d] * weight[o, d]
//   pi[b,i,o] = sum_d text[b,i,d] * weight[o, 768+d]
//   out[b,i,j,o] = pi[b,i,o] + pj[b,j,o] + bias[o]
// out: 268 MB f32 -> write-BW bound (~40 us floor at fill's 6.8 TB/s).
//
// R5: (a) gemv restructured f4-per-thread (s_load:FMA 1:4 instead of 1:1 —
//     was SMEM-issue-bound ~10us); (b) bcast register-tiled with PLAIN stores
//     at 32 waves/CU + XCD swizzle (R3 tile was confounded by nt-stores).
//
// ws layout (floats):
//   WT  [768][512]      : WT[d][h*256+o] = weight[o][h*768+d]   (393216 floats)
//   P   [2][1024][256]  : P[0]=pj, P[1]=pi+bias                 (524288 floats)

#define DDIM 768
#define WT_FLOATS (768 * 512)
#define P_HALF (1024 * 256)

typedef float f4 __attribute__((ext_vector_type(4)));

// ---- tiled weight transpose: weight[256][1536] -> WT[768][512] ----
__global__ __launch_bounds__(256) void k_transpose(const float* __restrict__ W,
                                                   float* __restrict__ WT) {
    __shared__ float t[32][33];
    const int c0 = blockIdx.x * 32;
    const int o0 = blockIdx.y * 32;
    const int tx = threadIdx.x & 31, ty = threadIdx.x >> 5;
#pragma unroll
    for (int yy = ty; yy < 32; yy += 8)
        t[yy][tx] = W[(size_t)(o0 + yy) * 1536 + c0 + tx];
    __syncthreads();
#pragma unroll
    for (int yy = ty; yy < 32; yy += 8) {
        int c = c0 + yy;
        int h = (c >= 768) ? 1 : 0;
        int d = c - h * 768;
        WT[(size_t)d * 512 + h * 256 + o0 + tx] = t[tx][yy];
    }
}

// ---- P computation v3: 4 rows/block, 8-way d-split, f4 per thread ----
// grid (256, 2), block 512. Thread: o64 = tid&63 (owns o4 = o64*4), dg = tid>>6.
// Per d-iter: 1 f4 weight load + 4 scalar text loads + 4 f4 FMAs.
__global__ __launch_bounds__(512) void k_gemv(const float* __restrict__ text,
                                              const float* __restrict__ bias,
                                              const float* __restrict__ WT,
                                              float* __restrict__ P) {
    __shared__ f4 red[8][4][64];   // 32 KB
    const int m0 = blockIdx.x * 4;
    const int h  = blockIdx.y;
    const int o64 = threadIdx.x & 63;
    const int dg  = __builtin_amdgcn_readfirstlane(threadIdx.x >> 6); // 0..7
    f4 acc[4];
#pragma unroll
    for (int r = 0; r < 4; ++r) acc[r] = (f4)0.0f;
    const float* t0 = text + (size_t)m0 * DDIM + dg * 96;    // wave-uniform rows
    const float* wt = WT + (size_t)(dg * 96) * 512 + h * 256 + o64 * 4;
#pragma unroll 8
    for (int d = 0; d < 96; ++d) {
        f4 w4 = *(const f4*)(wt + (size_t)d * 512);           // coalesced 1KB/wave
#pragma unroll
        for (int r = 0; r < 4; ++r) {
            float s = t0[(size_t)r * DDIM + d];               // uniform -> s_load
            acc[r] += w4 * s;
        }
    }
#pragma unroll
    for (int r = 0; r < 4; ++r) red[dg][r][o64] = acc[r];
    __syncthreads();
    if (threadIdx.x < 256) {
        int r = threadIdx.x >> 6, oo = threadIdx.x & 63;
        f4 s = red[0][r][oo];
#pragma unroll
        for (int g = 1; g < 8; ++g) s += red[g][r][oo];
        if (h) s += *(const f4*)(bias + oo * 4);              // fold bias into pi half
        *(f4*)(P + (size_t)h * P_HALF + (size_t)(m0 + r) * 256 + oo * 4) = s;
    }
}

// ---- broadcast add v4: register-tiled, plain stores, 32 waves/CU ----
// 2048 blocks x 256 thr. Tile 8 i-rows x 16 j-cols. XCD-swizzled block id.
// Thread: o4=(tid&63)*4, jg=tid>>6 owns j = jt*16+jg*4+k. pj in regs (4 f4);
// pi loaded 4 rows at a time; inner loop = pure add+store (no per-iter loads).
__global__ __launch_bounds__(256) void k_bcast(const float* __restrict__ P,
                                               float* __restrict__ out) {
    const int bid = blockIdx.x;
    const int wg  = (bid & 7) * 256 + (bid >> 3);   // 8 XCDs x 256 contiguous
    const int it  = wg & 127;                        // 128 i-tiles of 8 rows
    const int jt  = wg >> 7;                         // 16 j-tiles of 16 cols
    const int b   = it >> 5;
    const int o4  = (threadIdx.x & 63) * 4;
    const int jg  = threadIdx.x >> 6;
    const int r0  = it * 8;
    const int j0  = jt * 16 + jg * 4;

    f4 pj4[4];
    const float* pjb = P + ((size_t)b * 256 + j0) * 256 + o4;
#pragma unroll
    for (int k = 0; k < 4; ++k) pj4[k] = *(const f4*)(pjb + k * 256);

    const float* pib = P + P_HALF + (size_t)r0 * 256 + o4;
    float* outb = out + (size_t)r0 * 65536 + (size_t)j0 * 256 + o4;
#pragma unroll
    for (int ic = 0; ic < 2; ++ic) {
        f4 pi4[4];
#pragma unroll
        for (int m = 0; m < 4; ++m)
            pi4[m] = *(const f4*)(pib + (size_t)(ic * 4 + m) * 256);
#pragma unroll
        for (int m = 0; m < 4; ++m) {
            float* o_i = outb + (size_t)(ic * 4 + m) * 65536;
#pragma unroll
            for (int k = 0; k < 4; ++k)
                *(f4*)(o_i + k * 256) = pi4[m] + pj4[k];      // plain store
        }
    }
}

extern "C" void kernel_launch(void* const* d_in, const int* in_sizes, int n_in,
                              void* d_out, int out_size, void* d_ws, size_t ws_size,
                              hipStream_t stream) {
    const float* text   = (const float*)d_in[0];   // [4][256][768]
    const float* weight = (const float*)d_in[1];   // [256][1536]
    const float* bias   = (const float*)d_in[2];   // [256]
    float* out = (float*)d_out;                    // [4][256][256][256]
    float* WT  = (float*)d_ws;                     // [768][512]
    float* P   = WT + WT_FLOATS;                   // [2][1024][256]

    k_transpose<<<dim3(48, 8), 256, 0, stream>>>(weight, WT);
    k_gemv<<<dim3(256, 2), 512, 0, stream>>>(text, bias, WT, P);
    k_bcast<<<2048, 256, 0, stream>>>(P, out);
}